// Round 3
// baseline (160.101 us; speedup 1.0000x reference)
//
#include <hip/hip_runtime.h>
#include <math.h>

// SimpleInfoNCE: N=8192 rows (2048 groups of k=4), D=256, T=0.5.
// Plan: normalize rows -> bf16 hi/lo split -> symmetric MFMA GEMM over upper
// triangle with fused exp + masked row/col sums -> log/mean.
#define NROW 8192
#define DIM 256
#define NTILE 64            // 8192 / 128
#define NBLK 2080           // NTILE*(NTILE+1)/2 upper-triangle tiles

typedef float f32x4  __attribute__((ext_vector_type(4)));
typedef short short8 __attribute__((ext_vector_type(8)));   // 8 bf16 (4 VGPRs) — guide-verified operand type

__device__ __forceinline__ ushort f2bf_rne(float x) {
    unsigned u = __float_as_uint(x);
    unsigned r = (u + 0x7FFFu + ((u >> 16) & 1u)) >> 16;
    return (ushort)r;
}
__device__ __forceinline__ float bf2f(ushort h) {
    return __uint_as_float(((unsigned)h) << 16);
}

__global__ void zero_kernel(float* __restrict__ p, int n) {
    int i = blockIdx.x * blockDim.x + threadIdx.x;
    if (i < n) p[i] = 0.0f;
}

// One wave per row: compute 1/||f||, write normalized bf16 hi/lo in the
// MFMA-tiled layout: ushort_idx(row,k) = ((row/16)*32 + k/8)*128 + (row%16)*8 + k%8.
// Every 1024B chunk (16 rows x 8 k) is contiguous in global memory, so
// global_load_lds staging is linear AND frag ds_read_b128 is conflict-free,
// and the LDS image directly matches the MFMA A/B fragment layout
// (lane l: row = l&15, k = 8*(l>>4) + j).
__global__ __launch_bounds__(256) void prep_kernel(const float* __restrict__ f,
                                                   ushort* __restrict__ Hi,
                                                   ushort* __restrict__ Lo) {
    const int row = blockIdx.x * 4 + (threadIdx.x >> 6);
    const int l   = threadIdx.x & 63;
    float4 v = reinterpret_cast<const float4*>(f + (size_t)row * DIM)[l];
    float ss = v.x * v.x + v.y * v.y + v.z * v.z + v.w * v.w;
#pragma unroll
    for (int m = 32; m; m >>= 1) ss += __shfl_xor(ss, m, 64);
    const float inv = 1.0f / sqrtf(ss);
    float xv[4] = {v.x * inv, v.y * inv, v.z * inv, v.w * inv};
    ushort hv[4], lv[4];
#pragma unroll
    for (int i = 0; i < 4; ++i) {
        hv[i] = f2bf_rne(xv[i]);
        lv[i] = f2bf_rne(xv[i] - bf2f(hv[i]));
    }
    // k0 = 4*l:  k/8 = l>>1, k%8 = (l&1)*4
    size_t idx = (size_t)((row >> 4) * 32 + (l >> 1)) * 128 + (row & 15) * 8 + (l & 1) * 4;
    *reinterpret_cast<ushort4*>(&Hi[idx]) = make_ushort4(hv[0], hv[1], hv[2], hv[3]);
    *reinterpret_cast<ushort4*>(&Lo[idx]) = make_ushort4(lv[0], lv[1], lv[2], lv[3]);
}

__device__ __forceinline__ void gload16(const void* g, void* lp) {
    __builtin_amdgcn_global_load_lds((__attribute__((address_space(1))) void*)g,
                                     (__attribute__((address_space(3))) void*)lp, 16, 0, 0);
}

// 128x128 output tile per 256-thread block (4 waves, each 64x64 = 4x4 frags of
// 16x16x32 MFMA). K-loop: 3 passes (Hi·Hi, Hi·Lo, Lo·Hi) x 8 steps of K=32
// (lo·lo dropped: |err| ~2^-18, sim abs err ~4e-6).
// Epilogue: exp(2*sim), self/pos masks, row-sums (+ col-sums for off-diag tiles).
__global__ __launch_bounds__(256, 3) void infonce_mfma(const ushort* __restrict__ Hi,
                                                       const ushort* __restrict__ Lo,
                                                       float* __restrict__ all_sum,
                                                       float* __restrict__ pos_sum) {
    __shared__ ushort lds[2][2][4096];   // [dbuf][A/B][8KB tile], 32 KB total

    // unrank blockIdx -> upper-triangle (ti <= tj)
    int ti = 0, rem = blockIdx.x;
    while (rem >= NTILE - ti) { rem -= NTILE - ti; ++ti; }
    const int tj = ti + rem;

    const int tid = threadIdx.x;
    const int wid = tid >> 6, l = tid & 63;
    const int wr = wid >> 1, wc = wid & 1;   // wave tile = rows wr*64, cols wc*64

    f32x4 acc[4][4];
#pragma unroll
    for (int m = 0; m < 4; ++m)
#pragma unroll
        for (int n = 0; n < 4; ++n) acc[m][n] = (f32x4){0.f, 0.f, 0.f, 0.f};

    // stage step s into lds[buf]: each wave loads 2 A-chunks + 2 B-chunks of 1024B
#define STAGE(buf, s) do {                                                              \
        const int pass_ = (s) >> 3, kk_ = (s) & 7;                                      \
        const ushort* As_ = (pass_ == 2) ? Lo : Hi;                                     \
        const ushort* Bs_ = (pass_ == 1) ? Lo : Hi;                                     \
        const int f0_ = wid * 2, f1_ = f0_ + 1;                                         \
        gload16(&As_[(size_t)((ti * 8 + f0_) * 4096 + kk_ * 512) + l * 8],              \
                &lds[buf][0][f0_ * 512 + l * 8]);                                       \
        gload16(&As_[(size_t)((ti * 8 + f1_) * 4096 + kk_ * 512) + l * 8],              \
                &lds[buf][0][f1_ * 512 + l * 8]);                                       \
        gload16(&Bs_[(size_t)((tj * 8 + f0_) * 4096 + kk_ * 512) + l * 8],              \
                &lds[buf][1][f0_ * 512 + l * 8]);                                       \
        gload16(&Bs_[(size_t)((tj * 8 + f1_) * 4096 + kk_ * 512) + l * 8],              \
                &lds[buf][1][f1_ * 512 + l * 8]);                                       \
    } while (0)

#define COMPUTE(buf) do {                                                               \
        short8 af_[4], bf_[4];                                                          \
        _Pragma("unroll") for (int m = 0; m < 4; ++m)                                   \
            af_[m] = *reinterpret_cast<const short8*>(&lds[buf][0][(wr * 4 + m) * 512 + l * 8]); \
        _Pragma("unroll") for (int n = 0; n < 4; ++n)                                   \
            bf_[n] = *reinterpret_cast<const short8*>(&lds[buf][1][(wc * 4 + n) * 512 + l * 8]); \
        _Pragma("unroll") for (int m = 0; m < 4; ++m)                                   \
            _Pragma("unroll") for (int n = 0; n < 4; ++n)                               \
                acc[m][n] = __builtin_amdgcn_mfma_f32_16x16x32_bf16(af_[m], bf_[n], acc[m][n], 0, 0, 0); \
    } while (0)

    STAGE(0, 0);
#pragma unroll 2
    for (int s = 0; s < 24; ++s) {
        if (s < 23) STAGE((s + 1) & 1, s + 1);
        __syncthreads();             // compiler drains vmcnt before barrier
        COMPUTE(s & 1);
        __syncthreads();
    }

    // ---- epilogue: exp + masked sums ----
    const int rbase = ti * 128 + wr * 64;
    const int cbase = tj * 128 + wc * 64;
    const int h = l >> 4, c16 = l & 15;

    if (ti == tj) {
        // full diagonal tile: row sums cover this panel's cols; pos-mask lives here
#pragma unroll
        for (int m = 0; m < 4; ++m)
#pragma unroll
            for (int e = 0; e < 4; ++e) {
                const int row = rbase + m * 16 + h * 4 + e;
                float asum = 0.f, psum = 0.f;
#pragma unroll
                for (int n = 0; n < 4; ++n) {
                    const int col = cbase + n * 16 + c16;
                    float v = __expf(2.0f * acc[m][n][e]);
                    v = (row == col) ? 0.f : v;
                    asum += v;
                    psum += ((row >> 2) == (col >> 2)) ? v : 0.f;
                }
#pragma unroll
                for (int mk = 1; mk < 16; mk <<= 1) {
                    asum += __shfl_xor(asum, mk, 64);
                    psum += __shfl_xor(psum, mk, 64);
                }
                if (c16 == 0) {
                    atomicAdd(&all_sum[row], asum);
                    atomicAdd(&pos_sum[row], psum);
                }
            }
    } else {
        // off-diagonal: row sums for panel ti, col sums (symmetry) for panel tj
        float csum[4] = {0.f, 0.f, 0.f, 0.f};
#pragma unroll
        for (int m = 0; m < 4; ++m)
#pragma unroll
            for (int e = 0; e < 4; ++e) {
                const int row = rbase + m * 16 + h * 4 + e;
                float asum = 0.f;
#pragma unroll
                for (int n = 0; n < 4; ++n) {
                    float v = __expf(2.0f * acc[m][n][e]);
                    asum += v;
                    csum[n] += v;
                }
#pragma unroll
                for (int mk = 1; mk < 16; mk <<= 1) asum += __shfl_xor(asum, mk, 64);
                if (c16 == 0) atomicAdd(&all_sum[row], asum);
            }
#pragma unroll
        for (int n = 0; n < 4; ++n) {
            float cs = csum[n];
            cs += __shfl_xor(cs, 16, 64);
            cs += __shfl_xor(cs, 32, 64);
            if (h == 0) atomicAdd(&all_sum[cbase + n * 16 + c16], cs);
        }
    }
#undef STAGE
#undef COMPUTE
}

__global__ void loss_kernel(const float* __restrict__ all_sum,
                            const float* __restrict__ pos_sum,
                            float* __restrict__ out) {
    const int tid = threadIdx.x;
    float s = 0.0f;
    for (int i = tid; i < NROW; i += 256)
        s += logf(all_sum[i]) - logf(pos_sum[i]);
#pragma unroll
    for (int off = 32; off; off >>= 1) s += __shfl_xor(s, off, 64);
    __shared__ float red[4];
    if ((tid & 63) == 0) red[tid >> 6] = s;
    __syncthreads();
    if (tid == 0) out[0] = (red[0] + red[1] + red[2] + red[3]) / (float)NROW;
}

extern "C" void kernel_launch(void* const* d_in, const int* in_sizes, int n_in,
                              void* d_out, int out_size, void* d_ws, size_t ws_size,
                              hipStream_t stream) {
    const float* f = (const float*)d_in[0];
    float* out = (float*)d_out;

    float*  all_sum = (float*)d_ws;                    // 8192 f32
    float*  pos_sum = all_sum + NROW;                  // 8192 f32
    ushort* Hi      = (ushort*)(pos_sum + NROW);       // 8192*256 bf16 (4 MB)
    ushort* Lo      = Hi + (size_t)NROW * DIM;         // 8192*256 bf16 (4 MB)

    zero_kernel<<<64, 256, 0, stream>>>(all_sum, 2 * NROW);
    prep_kernel<<<NROW / 4, 256, 0, stream>>>(f, Hi, Lo);
    infonce_mfma<<<NBLK, 256, 0, stream>>>(Hi, Lo, all_sum, pos_sum);
    loss_kernel<<<1, 256, 0, stream>>>(all_sum, pos_sum, out);
}

// Round 4
// 141.646 us; speedup vs baseline: 1.1303x; 1.1303x over previous
//
#include <hip/hip_runtime.h>
#include <math.h>

// SimpleInfoNCE: N=8192 rows (2048 groups of k=4), D=256, T=0.5.
// normalize -> bf16 hi/lo split -> symmetric triangle MFMA GEMM (counted-vmcnt
// 3-buffer pipeline) with fused exp + masked row/col sums -> log/mean.
#define NROW 8192
#define DIM 256
#define NTILE 64            // 8192 / 128
#define NBLK 2080           // NTILE*(NTILE+1)/2 upper-triangle tiles
#define NT 24               // K-steps: 3 passes (HiHi, HiLo, LoHi) x 8 steps of K=32

typedef float f32x4  __attribute__((ext_vector_type(4)));
typedef short short8 __attribute__((ext_vector_type(8)));   // 8 bf16 (4 VGPRs)

__device__ __forceinline__ ushort f2bf_rne(float x) {
    unsigned u = __float_as_uint(x);
    unsigned r = (u + 0x7FFFu + ((u >> 16) & 1u)) >> 16;
    return (ushort)r;
}
__device__ __forceinline__ float bf2f(ushort h) {
    return __uint_as_float(((unsigned)h) << 16);
}

// One wave per row: 1/||f||, write normalized bf16 hi/lo in the MFMA-tiled
// layout: ushort_idx(row,k) = ((row/16)*32 + k/8)*128 + (row%16)*8 + k%8.
// Staging chunks are linear in global AND in LDS; frag ds_read_b128 is
// conflict-free (measured: SQ_LDS_BANK_CONFLICT = 0).
// Also zeroes the 16384-float sum buffer (8 floats per block) — replaces the
// separate zero_kernel launch.
__global__ __launch_bounds__(256) void prep_kernel(const float* __restrict__ f,
                                                   ushort* __restrict__ Hi,
                                                   ushort* __restrict__ Lo,
                                                   float* __restrict__ sums) {
    if (threadIdx.x < 8) sums[blockIdx.x * 8 + threadIdx.x] = 0.0f;
    const int row = blockIdx.x * 4 + (threadIdx.x >> 6);
    const int l   = threadIdx.x & 63;
    float4 v = reinterpret_cast<const float4*>(f + (size_t)row * DIM)[l];
    float ss = v.x * v.x + v.y * v.y + v.z * v.z + v.w * v.w;
#pragma unroll
    for (int m = 32; m; m >>= 1) ss += __shfl_xor(ss, m, 64);
    const float inv = 1.0f / sqrtf(ss);
    float xv[4] = {v.x * inv, v.y * inv, v.z * inv, v.w * inv};
    ushort hv[4], lv[4];
#pragma unroll
    for (int i = 0; i < 4; ++i) {
        hv[i] = f2bf_rne(xv[i]);
        lv[i] = f2bf_rne(xv[i] - bf2f(hv[i]));
    }
    size_t idx = (size_t)((row >> 4) * 32 + (l >> 1)) * 128 + (row & 15) * 8 + (l & 1) * 4;
    *reinterpret_cast<ushort4*>(&Hi[idx]) = make_ushort4(hv[0], hv[1], hv[2], hv[3]);
    *reinterpret_cast<ushort4*>(&Lo[idx]) = make_ushort4(lv[0], lv[1], lv[2], lv[3]);
}

__device__ __forceinline__ void gload16(const void* g, void* lp) {
    __builtin_amdgcn_global_load_lds((__attribute__((address_space(1))) void*)g,
                                     (__attribute__((address_space(3))) void*)lp, 16, 0, 0);
}

// 128x128 tile per 256-thread block (4 waves, each 64x64 = 4x4 frags of
// 16x16x32 MFMA). Counted-vmcnt 3-buffer pipeline:
//   tile t lives in buf[t%3]; during tile t we stage tile t+2 into
//   buf[(t+2)%3] (freed at t-1's barrier); step ends with vmcnt(4) (t+1's
//   stages forced complete, t+2's 4 loads stay in flight) + one s_barrier.
// Safety: stage into buf B issues only after the barrier ending B's last
// reader; vwait precedes the barrier so ALL waves' stages are visible after
// it; ds_read values land before each wave's own MFMA (register dep).
__global__ __launch_bounds__(256, 3) void infonce_mfma(const ushort* __restrict__ Hi,
                                                       const ushort* __restrict__ Lo,
                                                       float* __restrict__ all_sum,
                                                       float* __restrict__ pos_sum) {
    __shared__ ushort lds[3][2][4096];   // 3 bufs x (A,B) x 8KB = 48KB

    // unrank blockIdx -> upper-triangle (ti <= tj)
    int ti = 0, rem = blockIdx.x;
    while (rem >= NTILE - ti) { rem -= NTILE - ti; ++ti; }
    const int tj = ti + rem;

    const int tid = threadIdx.x;
    const int wid = tid >> 6, l = tid & 63;
    const int wr = wid >> 1, wc = wid & 1;

    f32x4 acc[4][4];
#pragma unroll
    for (int m = 0; m < 4; ++m)
#pragma unroll
        for (int n = 0; n < 4; ++n) acc[m][n] = (f32x4){0.f, 0.f, 0.f, 0.f};

#define STAGE(bufi, t) do {                                                             \
        const int pass_ = (t) >> 3, kk_ = (t) & 7;                                      \
        const ushort* As_ = (pass_ == 2) ? Lo : Hi;                                     \
        const ushort* Bs_ = (pass_ == 1) ? Lo : Hi;                                     \
        const int f0_ = wid * 2, f1_ = f0_ + 1;                                         \
        gload16(&As_[(size_t)((ti * 8 + f0_) * 4096 + kk_ * 512) + l * 8],              \
                &lds[bufi][0][f0_ * 512 + l * 8]);                                      \
        gload16(&As_[(size_t)((ti * 8 + f1_) * 4096 + kk_ * 512) + l * 8],              \
                &lds[bufi][0][f1_ * 512 + l * 8]);                                      \
        gload16(&Bs_[(size_t)((tj * 8 + f0_) * 4096 + kk_ * 512) + l * 8],              \
                &lds[bufi][1][f0_ * 512 + l * 8]);                                      \
        gload16(&Bs_[(size_t)((tj * 8 + f1_) * 4096 + kk_ * 512) + l * 8],              \
                &lds[bufi][1][f1_ * 512 + l * 8]);                                      \
    } while (0)

#define VWAIT(n) asm volatile("s_waitcnt vmcnt(" #n ")" ::: "memory")

#define BODY(t, bR, bS) do {                                                            \
        short8 af_[4], bf_[4];                                                          \
        _Pragma("unroll") for (int m = 0; m < 4; ++m)                                   \
            af_[m] = *reinterpret_cast<const short8*>(&lds[bR][0][(wr * 4 + m) * 512 + l * 8]); \
        _Pragma("unroll") for (int n = 0; n < 4; ++n)                                   \
            bf_[n] = *reinterpret_cast<const short8*>(&lds[bR][1][(wc * 4 + n) * 512 + l * 8]); \
        if ((t) + 2 < NT) STAGE(bS, (t) + 2);                                           \
        __builtin_amdgcn_s_setprio(1);                                                  \
        _Pragma("unroll") for (int m = 0; m < 4; ++m)                                   \
            _Pragma("unroll") for (int n = 0; n < 4; ++n)                               \
                acc[m][n] = __builtin_amdgcn_mfma_f32_16x16x32_bf16(af_[m], bf_[n], acc[m][n], 0, 0, 0); \
        __builtin_amdgcn_s_setprio(0);                                                  \
        if ((t) + 2 < NT) { VWAIT(4); } else { VWAIT(0); }                              \
        __builtin_amdgcn_s_barrier();                                                   \
    } while (0)

    // prologue: tiles 0,1 staged; own tile-0 loads landed; barrier -> all landed
    STAGE(0, 0);
    STAGE(1, 1);
    VWAIT(4);
    __builtin_amdgcn_s_barrier();

#pragma unroll 1
    for (int tb = 0; tb < NT; tb += 3) {
        BODY(tb + 0, 0, 2);
        BODY(tb + 1, 1, 0);
        BODY(tb + 2, 2, 1);
    }

    // ---- epilogue: exp + masked sums ----
    const int rbase = ti * 128 + wr * 64;
    const int cbase = tj * 128 + wc * 64;
    const int h = l >> 4, c16 = l & 15;

    if (ti == tj) {
#pragma unroll
        for (int m = 0; m < 4; ++m)
#pragma unroll
            for (int e = 0; e < 4; ++e) {
                const int row = rbase + m * 16 + h * 4 + e;
                float asum = 0.f, psum = 0.f;
#pragma unroll
                for (int n = 0; n < 4; ++n) {
                    const int col = cbase + n * 16 + c16;
                    float v = __expf(2.0f * acc[m][n][e]);
                    v = (row == col) ? 0.f : v;
                    asum += v;
                    psum += ((row >> 2) == (col >> 2)) ? v : 0.f;
                }
#pragma unroll
                for (int mk = 1; mk < 16; mk <<= 1) {
                    asum += __shfl_xor(asum, mk, 64);
                    psum += __shfl_xor(psum, mk, 64);
                }
                if (c16 == 0) {
                    atomicAdd(&all_sum[row], asum);
                    atomicAdd(&pos_sum[row], psum);
                }
            }
    } else {
        float csum[4] = {0.f, 0.f, 0.f, 0.f};
#pragma unroll
        for (int m = 0; m < 4; ++m)
#pragma unroll
            for (int e = 0; e < 4; ++e) {
                const int row = rbase + m * 16 + h * 4 + e;
                float asum = 0.f;
#pragma unroll
                for (int n = 0; n < 4; ++n) {
                    float v = __expf(2.0f * acc[m][n][e]);
                    asum += v;
                    csum[n] += v;
                }
#pragma unroll
                for (int mk = 1; mk < 16; mk <<= 1) asum += __shfl_xor(asum, mk, 64);
                if (c16 == 0) atomicAdd(&all_sum[row], asum);
            }
#pragma unroll
        for (int n = 0; n < 4; ++n) {
            float cs = csum[n];
            cs += __shfl_xor(cs, 16, 64);
            cs += __shfl_xor(cs, 32, 64);
            if (h == 0) atomicAdd(&all_sum[cbase + n * 16 + c16], cs);
        }
    }
#undef STAGE
#undef VWAIT
#undef BODY
}

__global__ __launch_bounds__(1024) void loss_kernel(const float* __restrict__ all_sum,
                                                    const float* __restrict__ pos_sum,
                                                    float* __restrict__ out) {
    const int tid = threadIdx.x;
    float s = 0.0f;
#pragma unroll
    for (int r = 0; r < 8; ++r) {
        const int i = tid + r * 1024;
        s += __logf(all_sum[i]) - __logf(pos_sum[i]);
    }
#pragma unroll
    for (int off = 32; off; off >>= 1) s += __shfl_xor(s, off, 64);
    __shared__ float red[16];
    if ((tid & 63) == 0) red[tid >> 6] = s;
    __syncthreads();
    if (tid == 0) {
        float tot = 0.f;
#pragma unroll
        for (int i = 0; i < 16; ++i) tot += red[i];
        out[0] = tot / (float)NROW;
    }
}

extern "C" void kernel_launch(void* const* d_in, const int* in_sizes, int n_in,
                              void* d_out, int out_size, void* d_ws, size_t ws_size,
                              hipStream_t stream) {
    const float* f = (const float*)d_in[0];
    float* out = (float*)d_out;

    float*  all_sum = (float*)d_ws;                    // 8192 f32
    float*  pos_sum = all_sum + NROW;                  // 8192 f32
    ushort* Hi      = (ushort*)(pos_sum + NROW);       // 8192*256 bf16 (4 MB)
    ushort* Lo      = Hi + (size_t)NROW * DIM;         // 8192*256 bf16 (4 MB)

    prep_kernel<<<NROW / 4, 256, 0, stream>>>(f, Hi, Lo, all_sum);
    infonce_mfma<<<NBLK, 256, 0, stream>>>(Hi, Lo, all_sum, pos_sum);
    loss_kernel<<<1, 1024, 0, stream>>>(all_sum, pos_sum, out);
}